// Round 2
// baseline (97.433 us; speedup 1.0000x reference)
//
#include <hip/hip_runtime.h>

#define NBINS 15
#define NTHREADS 256
#define NWAVES 4          // 256 / 64
#define NBLOCKS 2048      // memory-bound: ~8 blocks/CU, grid-stride

// Streaming pass, pure-register accumulation.
// S[k] = sum over elements with p > k/15 of t, where t = p - acc.
// Then per-bin (sum_conf - sum_acc) = S[b] - S[b+1]  (S[15] == 0), and the
// k=0 compare (p > 0) IS the reference's validity mask.
__global__ __launch_bounds__(NTHREADS) void ece_partial_kernel(
    const float* __restrict__ logits,
    const int* __restrict__ labels,
    float* __restrict__ partials,
    int n)
{
    float S[NBINS];
    #pragma unroll
    for (int k = 0; k < NBINS; ++k) S[k] = 0.0f;

    const int tid  = threadIdx.x;
    const int lane = tid & 63;
    const int w    = tid >> 6;

    const int n4 = n >> 2;
    const float4* L4 = (const float4*)logits;
    const int4*   Y4 = (const int4*)labels;
    const int stride = NBLOCKS * NTHREADS;

    for (int i = blockIdx.x * NTHREADS + tid; i < n4; i += stride) {
        float4 x = L4[i];
        int4   y = Y4[i];
        #pragma unroll
        for (int j = 0; j < 4; ++j) {
            float xv = (&x.x)[j];
            int   yv = (&y.x)[j];
            float p = 1.0f / (1.0f + __expf(-xv));
            float a = ((p > 0.5f) == (yv != 0)) ? 1.0f : 0.0f;
            float t = p - a;
            #pragma unroll
            for (int k = 0; k < NBINS; ++k) {
                const float edge = (float)k / 15.0f;   // folded at compile time
                S[k] += (p > edge) ? t : 0.0f;
            }
        }
    }

    // scalar tail (n not a multiple of 4) — block 0 only
    if (blockIdx.x == 0) {
        for (int i = (n4 << 2) + tid; i < n; i += NTHREADS) {
            float xv = logits[i];
            int   yv = labels[i];
            float p = 1.0f / (1.0f + __expf(-xv));
            float a = ((p > 0.5f) == (yv != 0)) ? 1.0f : 0.0f;
            float t = p - a;
            #pragma unroll
            for (int k = 0; k < NBINS; ++k) {
                const float edge = (float)k / 15.0f;
                S[k] += (p > edge) ? t : 0.0f;
            }
        }
    }

    // per-wave butterfly reduce, then cross-wave via tiny LDS
    __shared__ float wavesum[NWAVES][NBINS];
    #pragma unroll
    for (int k = 0; k < NBINS; ++k) {
        float s = S[k];
        #pragma unroll
        for (int m = 32; m >= 1; m >>= 1)
            s += __shfl_xor(s, m, 64);
        if (lane == 0) wavesum[w][k] = s;
    }
    __syncthreads();

    if (tid < NBINS) {
        float s = 0.0f;
        #pragma unroll
        for (int ww = 0; ww < NWAVES; ++ww) s += wavesum[ww][tid];
        partials[blockIdx.x * NBINS + tid] = s;
    }
}

// Deterministic fixed-order reduction of NBLOCKS x 15 partials, then
// ece = sum_b |S_b - S_{b+1}| / n   (S_15 == 0).
__global__ __launch_bounds__(NTHREADS) void ece_final_kernel(
    const float* __restrict__ partials,
    float* __restrict__ out,
    float inv_n)
{
    __shared__ double red[NBINS];
    const int t = threadIdx.x;
    if (t < 16 * NBINS) {             // 240 threads: 16 per bin
        const int b   = t >> 4;       // 0..14
        const int sub = t & 15;
        double s = 0.0;
        for (int k = sub; k < NBLOCKS; k += 16)
            s += (double)partials[k * NBINS + b];
        s += __shfl_xor(s, 8, 16);
        s += __shfl_xor(s, 4, 16);
        s += __shfl_xor(s, 2, 16);
        s += __shfl_xor(s, 1, 16);
        if (sub == 0) red[b] = s;
    }
    __syncthreads();
    if (t == 0) {
        double e = 0.0;
        #pragma unroll
        for (int b = 0; b < NBINS - 1; ++b)
            e += fabs(red[b] - red[b + 1]);
        e += fabs(red[NBINS - 1]);    // S_15 == 0
        out[0] = (float)(e * (double)inv_n);
    }
}

extern "C" void kernel_launch(void* const* d_in, const int* in_sizes, int n_in,
                              void* d_out, int out_size, void* d_ws, size_t ws_size,
                              hipStream_t stream)
{
    const float* logits = (const float*)d_in[0];
    const int*   labels = (const int*)d_in[1];
    float* out      = (float*)d_out;
    float* partials = (float*)d_ws;   // NBLOCKS * 15 * 4 B = 120 KiB
    const int n = in_sizes[0];

    ece_partial_kernel<<<NBLOCKS, NTHREADS, 0, stream>>>(logits, labels, partials, n);
    ece_final_kernel<<<1, NTHREADS, 0, stream>>>(partials, out, 1.0f / (float)n);
}